// Round 8
// baseline (194.387 us; speedup 1.0000x reference)
//
#include <hip/hip_runtime.h>
#include <math.h>

// ---------------------------------------------------------------------------
// Grok5PhiCore: out = proj( softmax(QK^T*scale + phi_bias) V ).
// B=2, L=2048, D=1024, H=16, Dh=64.
//
// v7b (v7 with cvt_pkrtz type fix):
//  - v_transpose kernel ELIMINATED: QKV gemm epilogue writes vb directly in
//    the permuted d-major layout. A 4-aligned run of j maps to one chunk,
//    consecutive elems (c=((lg>>5)<<2)|((lg>>2)&3), e0=((lg>>4)&1)*4) ->
//    one packed b64 store per (i,j) v-fragment.
//  - prep fused into ONE kernel (cast + both weight transposes).
//  - attn: 128-j rounds (4 LDS buffers, 32 KB), 8 outstanding DMAs per wave,
//    two compute phases per barrier pair -> half the barrier rounds.
//  - everything else per v6: global_load_lds + global-side XOR swizzle,
//    S^T register-P trick, static-max softmax, ones-MFMA row sums,
//    XCD-locality GEMM swizzle.
//
// Workspace (48 MB, fp16):
//   xb    [4096][1024]   8 MB   x cast
//   wqkvT [3072][1024]   6 MB   w_qkv transposed
//   wpT   [1024][1024]   2 MB   w_proj transposed
//   qb    [32][2048][64] 8 MB   Q per head, PRE-SCALED by 0.125*log2e
//   kb    [32][2048][64] 8 MB   K per head
//   vb    [32][64][2048] 8 MB   V^T per head, j-permuted (written by gemm)
//   ctx   [4096][1024]   8 MB   attn output
// ---------------------------------------------------------------------------

typedef _Float16 f16;
typedef _Float16 f16x4 __attribute__((ext_vector_type(4)));
typedef _Float16 f16x8 __attribute__((ext_vector_type(8)));
typedef float f32x4 __attribute__((ext_vector_type(4)));

#define MFMA32(a, b, c) __builtin_amdgcn_mfma_f32_16x16x32_f16(a, b, c, 0, 0, 0)

static constexpr int Bsz = 2, Lseq = 2048, Dm = 1024, H = 16, Dh = 64;
static constexpr int Mtot = Bsz * Lseq;        // 4096
static constexpr int NQKV = 3 * Dm;            // 3072
static constexpr float PHI_F = 1.61803398874989484820f;
static constexpr float LOG2E = 1.44269504088896f;
static constexpr float QS = 0.125f * LOG2E;    // folded into stored q
static constexpr float CSTEP = 0.55417527999932633f;  // fract(64*phi)

// pack two floats -> two f16 (RTZ); returns via _Float16 lanes
__device__ __forceinline__ void pk2(float a, float b, f16* d) {
  auto v = __builtin_amdgcn_cvt_pkrtz(a, b);  // __fp16 ext_vector(2)
  d[0] = (f16)v[0];
  d[1] = (f16)v[1];
}

// async 16B global -> LDS (lds dest = wave-uniform base + lane*16)
__device__ __forceinline__ void load16_to_lds(const f16* g, f16* l) {
  __builtin_amdgcn_global_load_lds(
      (const __attribute__((address_space(1))) unsigned int*)g,
      (__attribute__((address_space(3))) unsigned int*)l, 16, 0, 0);
}

// ---------------- fused prep: cast x, transpose w_qkv, transpose w_proj ----
// grid: 4096 cast blocks + 3072 wqkv-transpose + 1024 wproj-transpose.
__global__ __launch_bounds__(256) void prep_kernel(
    const float* __restrict__ x, const float* __restrict__ wqkv,
    const float* __restrict__ wproj, f16* __restrict__ xb,
    f16* __restrict__ wqkvT, f16* __restrict__ wpT) {
  __shared__ float tile[32][33];
  int bid = blockIdx.x, tid = threadIdx.x;
  if (bid < 4096) {  // cast 4 elems/thread
    int i = bid * 1024 + tid * 4;
    float4 v = *reinterpret_cast<const float4*>(x + i);
    f16 t[4] = {(f16)v.x, (f16)v.y, (f16)v.z, (f16)v.w};
    *reinterpret_cast<uint2*>(xb + i) = *reinterpret_cast<uint2*>(t);
    return;
  }
  const float* in;
  f16* out;
  int K, N, n0, k0;
  if (bid < 4096 + 3072) {
    int b2 = bid - 4096;
    in = wqkv; out = wqkvT; K = Dm; N = NQKV;
    n0 = (b2 % 96) * 32; k0 = (b2 / 96) * 32;
  } else {
    int b2 = bid - 7168;
    in = wproj; out = wpT; K = Dm; N = Dm;
    n0 = (b2 & 31) * 32; k0 = (b2 >> 5) * 32;
  }
  int tx = tid & 31, ty = tid >> 5;  // 32 x 8
#pragma unroll
  for (int r = 0; r < 32; r += 8)
    tile[ty + r][tx] = in[(size_t)(k0 + ty + r) * N + n0 + tx];
  __syncthreads();
#pragma unroll
  for (int r = 0; r < 32; r += 8)
    out[(size_t)(n0 + ty + r) * K + k0 + tx] = (f16)tile[tx][ty + r];
}

// ---------------- GEMM: C[M,N] = A[M,K] * Bt[N,K]^T  (fp16, fp32 acc) ------
// m97-style: global_load_lds(16B) staging, BK=64, unpadded LDS with
// global-side XOR chunk swizzle. MODE 0: 128x128 tile, QKV epilogue
// (v written directly in permuted d-major). MODE 1: 64x128, fp32 out + bias.
template <int MODE>
__global__ __launch_bounds__(256) void gemm_f16(
    const f16* __restrict__ A, const f16* __restrict__ Bt,
    int M, int N, int K,
    f16* __restrict__ qb, f16* __restrict__ kb, f16* __restrict__ vb,
    float* __restrict__ out, const float* __restrict__ bias) {
  constexpr int BM = (MODE == 0) ? 128 : 64;
  constexpr int MI = BM / 32;          // m-frags per wave (4 or 2)
  constexpr int AI = BM / 32;          // A staging iters per thread
  __shared__ f16 As[BM * 64];
  __shared__ f16 Bs[128 * 64];

  int tid = threadIdx.x;
  int wave = tid >> 6, lane = tid & 63;
  int quad = lane >> 4, l16 = lane & 15;
  int wm = (wave >> 1) * (MI * 16), wn = (wave & 1) * 64;

  // XCD-locality swizzle (1-D grid)
  int lid = blockIdx.x;
  int xcd = lid & 7, t = lid >> 3;
  int m0, n0;
  if (MODE == 0) {  // 32m x 24n blocks; XCD region = 8m x 12n
    int mg = xcd >> 1, ng = xcd & 1;
    m0 = (mg * 8 + t / 12) * 128;
    n0 = (ng * 12 + t % 12) * 128;
  } else {          // 64m x 8n blocks; XCD region = 8m x 8n
    m0 = (xcd * 8 + (t >> 3)) * 64;
    n0 = (t & 7) * 128;
  }

  // staging: lds chunk (64*it + lane) holds global chunk gu of row
  // (8*it + lane>>3), gu = (lane&7) ^ (lane>>3)
  const int gu = (lane & 7) ^ (lane >> 3);
  const f16* gA[AI];
  f16* lA[AI];
#pragma unroll
  for (int i = 0; i < AI; i++) {
    int it = wave * AI + i;
    gA[i] = A + (size_t)(m0 + it * 8 + (lane >> 3)) * K + gu * 8;
    lA[i] = As + it * 512;
  }
  const f16* gB[4];
  f16* lB[4];
#pragma unroll
  for (int i = 0; i < 4; i++) {
    int it = wave * 4 + i;
    gB[i] = Bt + (size_t)(n0 + it * 8 + (lane >> 3)) * K + gu * 8;
    lB[i] = Bs + it * 512;
  }

  f32x4 acc[MI][4] = {};

  for (int k0 = 0; k0 < K; k0 += 64) {
#pragma unroll
    for (int i = 0; i < AI; i++) load16_to_lds(gA[i] + k0, lA[i]);
#pragma unroll
    for (int i = 0; i < 4; i++) load16_to_lds(gB[i] + k0, lB[i]);
    __syncthreads();  // drains vmcnt before barrier
#pragma unroll
    for (int s = 0; s < 2; s++) {
      f16x8 a[MI], b[4];
#pragma unroll
      for (int i = 0; i < MI; i++) {
        int row = wm + i * 16 + l16;
        a[i] = *reinterpret_cast<const f16x8*>(
            As + row * 64 + (((s * 4 + quad) ^ (l16 & 7)) * 8));
      }
#pragma unroll
      for (int j = 0; j < 4; j++) {
        int row = wn + j * 16 + l16;
        b[j] = *reinterpret_cast<const f16x8*>(
            Bs + row * 64 + (((s * 4 + quad) ^ (l16 & 7)) * 8));
      }
#pragma unroll
      for (int i = 0; i < MI; i++)
#pragma unroll
        for (int j = 0; j < 4; j++)
          acc[i][j] = MFMA32(a[i], b[j], acc[i][j]);
    }
    __syncthreads();
  }

  // epilogue: C/D layout col = lane&15, row = quad*4 + reg
  if (MODE == 1) {
#pragma unroll
    for (int i = 0; i < MI; i++)
#pragma unroll
      for (int j = 0; j < 4; j++) {
        int n = n0 + wn + j * 16 + l16;
#pragma unroll
        for (int r = 0; r < 4; r++) {
          int m = m0 + wm + i * 16 + quad * 4 + r;
          out[(size_t)m * N + n] = acc[i][j][r] + bias[n];
        }
      }
    return;
  }
  int ty = n0 >> 10;  // wave-uniform: 0=q 1=k 2=v
  if (ty < 2) {
    f16* dst = (ty == 0) ? qb : kb;
    float sc = (ty == 0) ? QS : 1.0f;
#pragma unroll
    for (int i = 0; i < MI; i++)
#pragma unroll
      for (int j = 0; j < 4; j++) {
        int n = n0 + wn + j * 16 + l16;
        int h = (n & 1023) >> 6, dh = n & 63;
#pragma unroll
        for (int r = 0; r < 4; r++) {
          int m = m0 + wm + i * 16 + quad * 4 + r;
          int b = m >> 11, l = m & 2047;
          dst[(((size_t)(b * H + h)) * Lseq + l) * Dh + dh] =
              (f16)(acc[i][j][r] * sc);
        }
      }
  } else {
    // v: permuted d-major vb[bh][dh][64grp*64 + c*8 + e0 + r], b64 stores
#pragma unroll
    for (int i = 0; i < MI; i++) {
      int mb = m0 + wm + i * 16 + quad * 4;  // 4-aligned l run
      int b = mb >> 11, l = mb & 2047;
      int L0 = l & ~63, lg = l & 63;
      int c = ((lg >> 5) << 2) | ((lg >> 2) & 3);
      int e0 = ((lg >> 4) & 1) * 4;
      int off = L0 + c * 8 + e0;
#pragma unroll
      for (int j = 0; j < 4; j++) {
        int n = n0 + wn + j * 16 + l16;
        int h = (n & 1023) >> 6, dh = n & 63;
        f16x4 v;
        pk2(acc[i][j][0], acc[i][j][1], (f16*)&v);
        pk2(acc[i][j][2], acc[i][j][3], ((f16*)&v) + 2);
        *reinterpret_cast<uint2*>(
            vb + ((size_t)(b * H + h) * Dh + dh) * Lseq + off) =
            *reinterpret_cast<uint2*>(&v);
      }
    }
  }
}

// ---------------- flash attention v7 ---------------------------------------
// grid: (L/64, B*H), 256 threads. Wave w: qhalf = w&1 (32 q), jhalf = w>>1
// (32 j of each 64-j tile). 128-j rounds: stage Ks0/Vs0/Ks1/Vs1 (8 DMAs per
// wave), two compute phases per barrier pair. Row sums via ones-A MFMA.
__global__ __launch_bounds__(256, 4) void attn_kernel(
    const f16* __restrict__ qb,   // [BH][L][64], pre-scaled by QS
    const f16* __restrict__ kb,   // [BH][L][64]
    const f16* __restrict__ vb,   // [BH][64][L], j-permuted
    f16* __restrict__ ctx) {      // [B*L][1024]
  __shared__ __align__(16) unsigned char smem[32768];
  f16* Ks0 = (f16*)smem;            // [64][64] XOR-swizzled
  f16* Ks1 = (f16*)(smem + 8192);
  f16* Vs0 = (f16*)(smem + 16384);  // [64][64] permuted + swizzled
  f16* Vs1 = (f16*)(smem + 24576);

  int bh = blockIdx.y;
  int q0 = blockIdx.x * 64;
  int tid = threadIdx.x, wave = tid >> 6, lane = tid & 63;
  int quad = lane >> 4, l16 = lane & 15;
  int jhalf = wave >> 1, qhalf = wave & 1;

  // Q B-frags (B[k=quad*8+t][n=l16] = Q[q=l16][d=quad*8+t])
  f16x8 qfrag[2][2];
  float pq[2];
#pragma unroll
  for (int set = 0; set < 2; set++) {
    int q = q0 + qhalf * 32 + set * 16 + l16;
    const f16* Qrow = qb + ((size_t)bh * Lseq + q) * Dh;
    qfrag[set][0] = *reinterpret_cast<const f16x8*>(Qrow + quad * 8);
    qfrag[set][1] = *reinterpret_cast<const f16x8*>(Qrow + 32 + quad * 8);
    pq[set] = fmodf((float)q * PHI_F, 1.0f);
  }

  float pk[2][4];
#pragma unroll
  for (int jb = 0; jb < 2; jb++)
#pragma unroll
    for (int r = 0; r < 4; r++) {
      int j = jhalf * 32 + jb * 16 + quad * 4 + r;
      pk[jb][r] = fmodf((float)j * PHI_F, 1.0f);
    }

  // staging pointers (global-side XOR swizzle; lds dest = base + lane*16)
  const f16* Kbh = kb + (size_t)bh * Lseq * Dh;
  const f16* Vbh = vb + (size_t)bh * Dh * Lseq;
  const int gu = (lane & 7) ^ (lane >> 3);
  const f16* gK[2];
  const f16* gV[2];
  f16* lK[2];
  f16* lV[2];
#pragma unroll
  for (int i = 0; i < 2; i++) {
    int g8 = (wave * 2 + i) * 8 + (lane >> 3);
    gK[i] = Kbh + (size_t)g8 * Dh + gu * 8;    // + j0*Dh per tile
    gV[i] = Vbh + (size_t)g8 * Lseq + gu * 8;  // + j0 per tile
    lK[i] = Ks0 + (wave * 2 + i) * 512;
    lV[i] = Vs0 + (wave * 2 + i) * 512;
  }

  const f16 one = (f16)1.0f;
  const f16x8 ones8 = {one, one, one, one, one, one, one, one};

  f32x4 acc_o[2][4] = {};  // [set][dblk]  O^T: row d=quad*4+r, col q=l16
  f32x4 acc_l[2] = {};     // row sums via ones-MFMA

  auto phase = [&](const f16* Ksp, const f16* Vsp) {
    // S^T = K * Q^T over this wave's 32 j's
    f32x4 accs[2][2] = {};
#pragma unroll
    for (int s = 0; s < 2; s++)
#pragma unroll
      for (int jb = 0; jb < 2; jb++) {
        f16x8 kf = *reinterpret_cast<const f16x8*>(
            Ksp + (jhalf * 32 + jb * 16 + l16) * 64 +
            (((s * 4 + quad) ^ (l16 & 7)) * 8));
        accs[0][jb] = MFMA32(kf, qfrag[0][s], accs[0][jb]);
        accs[1][jb] = MFMA32(kf, qfrag[1][s], accs[1][jb]);
      }
    // p = exp2(s2 - |pq-pk|*log2e); K=32 PV B-frag (permuted k-order)
    f16x8 pf8[2];
#pragma unroll
    for (int set = 0; set < 2; set++) {
#pragma unroll
      for (int jb = 0; jb < 2; jb++) {
        float p[4];
#pragma unroll
        for (int r = 0; r < 4; r++) {
          float d = pq[set] - pk[jb][r];
          float arg = fmaf(-LOG2E, fabsf(d), accs[set][jb][r]);
          p[r] = __builtin_amdgcn_exp2f(arg);
        }
        pk2(p[0], p[1], ((f16*)&pf8[set]) + jb * 4);
        pk2(p[2], p[3], ((f16*)&pf8[set]) + jb * 4 + 2);
      }
      acc_l[set] = MFMA32(ones8, pf8[set], acc_l[set]);
    }
#pragma unroll
    for (int jb = 0; jb < 2; jb++)
#pragma unroll
      for (int r = 0; r < 4; r++)
        pk[jb][r] = __builtin_amdgcn_fractf(pk[jb][r] + CSTEP);
    // O^T += V^T * P^T
#pragma unroll
    for (int dblk = 0; dblk < 4; dblk++) {
      int row = dblk * 16 + l16;
      f16x8 va = *reinterpret_cast<const f16x8*>(
          Vsp + row * 64 + (((jhalf * 4 + quad) ^ (l16 & 7)) * 8));
      acc_o[0][dblk] = MFMA32(va, pf8[0], acc_o[0][dblk]);
      acc_o[1][dblk] = MFMA32(va, pf8[1], acc_o[1][dblk]);
    }
  };

  for (int j0 = 0; j0 < Lseq; j0 += 128) {
    __syncthreads();  // prior round's frag reads complete
#pragma unroll
    for (int i = 0; i < 2; i++) {
      load16_to_lds(gK[i] + (size_t)j0 * Dh, lK[i]);
      load16_to_lds(gK[i] + (size_t)(j0 + 64) * Dh, lK[i] + 4096);
      load16_to_lds(gV[i] + j0, lV[i]);
      load16_to_lds(gV[i] + j0 + 64, lV[i] + 4096);
    }
    __syncthreads();  // vmcnt drained before barrier
    phase(Ks0, Vs0);
    phase(Ks1, Vs1);
  }

  // combine jhalf partials: pure adds (static max => no rescale)
  __syncthreads();
  float* Oex = (float*)smem;              // [2 qhalf][2 set][4 dblk][16][16]
  float* Lex = (float*)(smem + 16384);    // [2 qhalf][2 set][16]
  if (jhalf == 1) {
#pragma unroll
    for (int set = 0; set < 2; set++) {
#pragma unroll
      for (int dblk = 0; dblk < 4; dblk++)
#pragma unroll
        for (int r = 0; r < 4; r++)
          Oex[(((qhalf * 2 + set) * 4 + dblk) * 16 + quad * 4 + r) * 16 + l16] =
              acc_o[set][dblk][r];
      if (quad == 0) Lex[(qhalf * 2 + set) * 16 + l16] = acc_l[set][0];
    }
  }
  __syncthreads();
  if (jhalf == 0) {
    int b = bh >> 4, h = bh & 15;
#pragma unroll
    for (int set = 0; set < 2; set++) {
      float ltot = acc_l[set][0] + Lex[(qhalf * 2 + set) * 16 + l16];
      float inv = 1.0f / ltot;
      int q = q0 + qhalf * 32 + set * 16 + l16;
      f16* crow = ctx + (size_t)(b * Lseq + q) * Dm + h * 64;
#pragma unroll
      for (int dblk = 0; dblk < 4; dblk++) {
        f16x4 o;
#pragma unroll
        for (int r = 0; r < 4; r++) {
          float full = acc_o[set][dblk][r] +
              Oex[(((qhalf * 2 + set) * 4 + dblk) * 16 + quad * 4 + r) * 16 + l16];
          o[r] = (f16)(full * inv);
        }
        *reinterpret_cast<uint2*>(crow + dblk * 16 + quad * 4) =
            *reinterpret_cast<uint2*>(&o);
      }
    }
  }
}

// ---------------------------------------------------------------------------
extern "C" void kernel_launch(void* const* d_in, const int* in_sizes, int n_in,
                              void* d_out, int out_size, void* d_ws, size_t ws_size,
                              hipStream_t stream) {
  const float* x      = (const float*)d_in[0];  // [2,2048,1024]
  const float* w_qkv  = (const float*)d_in[1];  // [1024,3072]
  const float* w_proj = (const float*)d_in[2];  // [1024,1024]
  const float* b_proj = (const float*)d_in[3];  // [1024]
  float* out = (float*)d_out;                   // [2,2048,1024]

  f16* xb    = (f16*)d_ws;                       // 4096*1024
  f16* wqkvT = xb + (size_t)Mtot * Dm;           // 3072*1024
  f16* wpT   = wqkvT + (size_t)NQKV * Dm;        // 1024*1024
  f16* qb    = wpT + (size_t)Dm * Dm;            // 32*2048*64
  f16* kb    = qb + (size_t)Bsz * H * Lseq * Dh;
  f16* vb    = kb + (size_t)Bsz * H * Lseq * Dh;
  f16* ctx   = vb + (size_t)Bsz * H * Lseq * Dh; // 4096*1024

  // fused prep: cast x + transpose both weights
  prep_kernel<<<8192, 256, 0, stream>>>(x, w_qkv, w_proj, xb, wqkvT, wpT);

  // QKV GEMM -> q (scaled), k l-major; v directly permuted d-major
  gemm_f16<0><<<768, 256, 0, stream>>>(
      xb, wqkvT, Mtot, NQKV, Dm, qb, kb, vb, nullptr, nullptr);

  // attention
  attn_kernel<<<dim3(Lseq / 64, Bsz * H), 256, 0, stream>>>(qb, kb, vb, ctx);

  // proj GEMM: [4096,1024] x [1024,1024] + bias (64x128 tiles)
  gemm_f16<1><<<512, 256, 0, stream>>>(
      ctx, wpT, Mtot, Dm, Dm, nullptr, nullptr, nullptr, out, b_proj);
}